// Round 1
// baseline (390.006 us; speedup 1.0000x reference)
//
#include <hip/hip_runtime.h>
#include <stdint.h>
#include <math.h>

typedef __attribute__((ext_vector_type(4))) int i32x4;

constexpr int D_DIM = 1280;   // embedding dim (lin1 K, lin2 N)
constexpr int H_DIM = 5120;   // mlp dim      (lin1 N, lin2 K)
constexpr int BM = 128, BN = 128, BK = 64;

__device__ __forceinline__ void gload_lds16(const void* g, void* l) {
  __builtin_amdgcn_global_load_lds(
      (const __attribute__((address_space(1))) void*)g,
      (__attribute__((address_space(3))) void*)l,
      16, 0, 0);
}

// ---- pack int32 (sign-extended int8 values) -> int8 -------------------------
__global__ void __launch_bounds__(256) k_pack(const int* __restrict__ in,
                                              int8_t* __restrict__ out,
                                              long n) {
  long i = ((long)blockIdx.x * 256 + threadIdx.x) * 16;
  if (i >= n) return;
  const int* p = in + i;
  i32x4 a = *(const i32x4*)(p);
  i32x4 b = *(const i32x4*)(p + 4);
  i32x4 c = *(const i32x4*)(p + 8);
  i32x4 d = *(const i32x4*)(p + 12);
  i32x4 r;
  r.x = (a.x & 255) | ((a.y & 255) << 8) | ((a.z & 255) << 16) | (a.w << 24);
  r.y = (b.x & 255) | ((b.y & 255) << 8) | ((b.z & 255) << 16) | (b.w << 24);
  r.z = (c.x & 255) | ((c.y & 255) << 8) | ((c.z & 255) << 16) | (c.w << 24);
  r.w = (d.x & 255) | ((d.y & 255) << 8) | ((d.z & 255) << 16) | (d.w << 24);
  *(i32x4*)(out + i) = r;
}

// ---- lin1: q = requant(gelu(x @ w1^T * a1 + b1)) ----------------------------
// A = X [mc, 1280] i8 row-major, B = W1 [5120, 1280] i8 row-major (NT GEMM)
__global__ void __launch_bounds__(256)
k_lin1(const int8_t* __restrict__ X, const int8_t* __restrict__ W1,
       const float* __restrict__ B1, const float* __restrict__ pa1,
       const float* __restrict__ psreq, int8_t* __restrict__ Q) {
  constexpr int K = D_DIM;
  constexpr int NTN = H_DIM / BN;  // 40
  const int bid = blockIdx.x;
  const int bn = bid % NTN;
  const int bm = bid / NTN;

  __shared__ __align__(16) int8_t As[BM * BK];
  __shared__ __align__(16) int8_t Bs[BN * BK];

  const int tid = threadIdx.x;
  const int lane = tid & 63;
  const int wid = tid >> 6;
  const int wr = wid >> 1;  // 2x2 waves, each owns 64x64
  const int wc = wid & 1;

  i32x4 acc[4][4] = {};

  const int8_t* Ag = X + (size_t)bm * BM * K;
  const int8_t* Bg = W1 + (size_t)bn * BN * K;

  const int srow = tid >> 2;        // 0..63
  const int scol = (tid & 3) << 4;  // 0,16,32,48

  for (int kt = 0; kt < K; kt += BK) {
    gload_lds16(Ag + (size_t)srow * K + kt + scol, As + tid * 16);
    gload_lds16(Ag + (size_t)(srow + 64) * K + kt + scol, As + 4096 + tid * 16);
    gload_lds16(Bg + (size_t)srow * K + kt + scol, Bs + tid * 16);
    gload_lds16(Bg + (size_t)(srow + 64) * K + kt + scol, Bs + 4096 + tid * 16);
    __syncthreads();  // compiler emits vmcnt(0) drain before barrier

    const int kb = (lane >> 4) << 4;           // per-lane K offset (16 B)
    const int ar = (wr << 6) + (lane & 15);    // A row within tile
    const int br = (wc << 6) + (lane & 15);    // B row (=N col) within tile
    i32x4 af[4], bf[4];
#pragma unroll
    for (int m = 0; m < 4; ++m)
      af[m] = *(const i32x4*)(As + (ar + m * 16) * BK + kb);
#pragma unroll
    for (int n = 0; n < 4; ++n)
      bf[n] = *(const i32x4*)(Bs + (br + n * 16) * BK + kb);
#pragma unroll
    for (int m = 0; m < 4; ++m)
#pragma unroll
      for (int n = 0; n < 4; ++n)
        acc[m][n] = __builtin_amdgcn_mfma_i32_16x16x64_i8(af[m], bf[n], acc[m][n], 0, 0, 0);
    __syncthreads();
  }

  const float a1 = *pa1;
  const float sreq = *psreq;
  // C/D layout (16x16): col = lane&15, row = (lane>>4)*4 + reg
  const int rowb = bm * BM + wr * 64 + ((lane >> 4) << 2);
  const int colb = bn * BN + wc * 64 + (lane & 15);
#pragma unroll
  for (int n = 0; n < 4; ++n) {
    const int col = colb + n * 16;
    const float bias = B1[col];
#pragma unroll
    for (int m = 0; m < 4; ++m) {
#pragma unroll
      for (int r = 0; r < 4; ++r) {
        const int row = rowb + m * 16 + r;
        float h = (float)acc[m][n][r] * a1 + bias;
        float g = 0.5f * h * (1.0f + erff(h * 0.70710678f));
        float qf = rintf(g / sreq);                    // round-half-even = np.round
        qf = fminf(127.0f, fmaxf(-128.0f, qf));
        Q[(size_t)row * H_DIM + col] = (int8_t)(int)qf;
      }
    }
  }
}

// ---- lin2: out = q @ w2^T * a2 + b2 -----------------------------------------
// A = Q [mc, 5120] i8 row-major, B = W2 [1280, 5120] i8 row-major (NT GEMM)
__global__ void __launch_bounds__(256)
k_lin2(const int8_t* __restrict__ Q, const int8_t* __restrict__ W2,
       const float* __restrict__ B2, const float* __restrict__ pa2,
       float* __restrict__ Out) {
  constexpr int K = H_DIM;
  constexpr int NTN = D_DIM / BN;  // 10
  const int bid = blockIdx.x;
  const int bn = bid % NTN;
  const int bm = bid / NTN;

  __shared__ __align__(16) int8_t As[BM * BK];
  __shared__ __align__(16) int8_t Bs[BN * BK];

  const int tid = threadIdx.x;
  const int lane = tid & 63;
  const int wid = tid >> 6;
  const int wr = wid >> 1;
  const int wc = wid & 1;

  i32x4 acc[4][4] = {};

  const int8_t* Ag = Q + (size_t)bm * BM * K;
  const int8_t* Bg = W2 + (size_t)bn * BN * K;

  const int srow = tid >> 2;
  const int scol = (tid & 3) << 4;

  for (int kt = 0; kt < K; kt += BK) {
    gload_lds16(Ag + (size_t)srow * K + kt + scol, As + tid * 16);
    gload_lds16(Ag + (size_t)(srow + 64) * K + kt + scol, As + 4096 + tid * 16);
    gload_lds16(Bg + (size_t)srow * K + kt + scol, Bs + tid * 16);
    gload_lds16(Bg + (size_t)(srow + 64) * K + kt + scol, Bs + 4096 + tid * 16);
    __syncthreads();

    const int kb = (lane >> 4) << 4;
    const int ar = (wr << 6) + (lane & 15);
    const int br = (wc << 6) + (lane & 15);
    i32x4 af[4], bf[4];
#pragma unroll
    for (int m = 0; m < 4; ++m)
      af[m] = *(const i32x4*)(As + (ar + m * 16) * BK + kb);
#pragma unroll
    for (int n = 0; n < 4; ++n)
      bf[n] = *(const i32x4*)(Bs + (br + n * 16) * BK + kb);
#pragma unroll
    for (int m = 0; m < 4; ++m)
#pragma unroll
      for (int n = 0; n < 4; ++n)
        acc[m][n] = __builtin_amdgcn_mfma_i32_16x16x64_i8(af[m], bf[n], acc[m][n], 0, 0, 0);
    __syncthreads();
  }

  const float a2 = *pa2;
  const int rowb = bm * BM + wr * 64 + ((lane >> 4) << 2);
  const int colb = bn * BN + wc * 64 + (lane & 15);
#pragma unroll
  for (int n = 0; n < 4; ++n) {
    const int col = colb + n * 16;
    const float bias = B2[col];
#pragma unroll
    for (int m = 0; m < 4; ++m) {
#pragma unroll
      for (int r = 0; r < 4; ++r) {
        const int row = rowb + m * 16 + r;
        Out[(size_t)row * D_DIM + col] = (float)acc[m][n][r] * a2 + bias;
      }
    }
  }
}

extern "C" void kernel_launch(void* const* d_in, const int* in_sizes, int n_in,
                              void* d_out, int out_size, void* d_ws, size_t ws_size,
                              hipStream_t stream) {
  (void)in_sizes; (void)n_in; (void)out_size;
  const int*   x32  = (const int*)d_in[0];
  const int*   w132 = (const int*)d_in[1];
  const float* b1   = (const float*)d_in[2];
  const int*   w232 = (const int*)d_in[3];
  const float* b2   = (const float*)d_in[4];
  const float* a1   = (const float*)d_in[5];
  const float* sreq = (const float*)d_in[6];
  const float* a2   = (const float*)d_in[7];
  float* out = (float*)d_out;

  const int M = 4 * 4096;                       // 16384 tokens
  const size_t WN = (size_t)H_DIM * D_DIM;      // 6,553,600 weights each

  int8_t* w1p  = (int8_t*)d_ws;
  int8_t* w2p  = w1p + WN;
  int8_t* base = w2p + WN;

  // chunk M so that (packed x chunk + q chunk) fits in remaining workspace
  size_t avail = ws_size > 2 * WN ? ws_size - 2 * WN : 0;
  size_t rows = avail / (size_t)(D_DIM + H_DIM);
  int Mc = (int)((rows / BM) * BM);
  if (Mc > M) Mc = M;
  if (Mc < BM) Mc = BM;

  // pack weights once per call (deterministic)
  k_pack<<<(int)(WN / 4096), 256, 0, stream>>>(w132, w1p, (long)WN);
  k_pack<<<(int)(WN / 4096), 256, 0, stream>>>(w232, w2p, (long)WN);

  for (int m0 = 0; m0 < M; m0 += Mc) {
    const int mc = (M - m0 < Mc) ? (M - m0) : Mc;
    int8_t* xp = base;
    int8_t* q  = base + (size_t)Mc * D_DIM;
    const size_t nx = (size_t)mc * D_DIM;
    k_pack<<<(int)(nx / 4096), 256, 0, stream>>>(x32 + (size_t)m0 * D_DIM, xp, (long)nx);
    k_lin1<<<(mc / BM) * (H_DIM / BN), 256, 0, stream>>>(xp, w1p, b1, a1, sreq, q);
    k_lin2<<<(mc / BM) * (D_DIM / BN), 256, 0, stream>>>(q, w2p, b2, a2,
                                                         out + (size_t)m0 * D_DIM);
  }
}

// Round 2
// 347.146 us; speedup vs baseline: 1.1235x; 1.1235x over previous
//
#include <hip/hip_runtime.h>
#include <stdint.h>
#include <math.h>

typedef __attribute__((ext_vector_type(4))) int i32x4;

constexpr int D_DIM = 1280;   // embedding dim (lin1 K, lin2 N)
constexpr int H_DIM = 5120;   // mlp dim      (lin1 N, lin2 K)
constexpr int BM = 128, BN = 128, BK = 64;

__device__ __forceinline__ void gload_lds16(const void* g, void* l) {
  __builtin_amdgcn_global_load_lds(
      (const __attribute__((address_space(1))) void*)g,
      (__attribute__((address_space(3))) void*)l,
      16, 0, 0);
}

// bijective XCD swizzle (m204): contiguous chunk of blocks per XCD
__device__ __forceinline__ int xcd_swizzle(int bid, int nwg) {
  const int xcd = bid & 7, local = bid >> 3;
  const int q = nwg >> 3, r = nwg & 7;
  return (xcd < r ? xcd * (q + 1) : r * (q + 1) + (xcd - r) * q) + local;
}

// branchless erf, Abramowitz-Stegun 7.1.26, |eps| <= 1.5e-7
__device__ __forceinline__ float gelu_fast(float h) {
  const float x = h * 0.70710678118f;
  const float ax = fabsf(x);
  const float t = __frcp_rn(__builtin_fmaf(0.3275911f, ax, 1.0f));
  float p = __builtin_fmaf(1.061405429f, t, -1.453152027f);
  p = __builtin_fmaf(p, t, 1.421413741f);
  p = __builtin_fmaf(p, t, -0.284496736f);
  p = __builtin_fmaf(p, t, 0.254829592f);
  p *= t;
  const float e = __expf(-x * x);            // hw v_exp_f32 path
  const float erf_ax = __builtin_fmaf(-p, e, 1.0f);
  const float erf_x = copysignf(erf_ax, x);
  return 0.5f * h * (1.0f + erf_x);
}

// ---- pack int32 (sign-extended int8 values) -> int8 -------------------------
__global__ void __launch_bounds__(256) k_pack(const int* __restrict__ in,
                                              int8_t* __restrict__ out,
                                              long n) {
  long i = ((long)blockIdx.x * 256 + threadIdx.x) * 16;
  if (i >= n) return;
  const int* p = in + i;
  i32x4 a = *(const i32x4*)(p);
  i32x4 b = *(const i32x4*)(p + 4);
  i32x4 c = *(const i32x4*)(p + 8);
  i32x4 d = *(const i32x4*)(p + 12);
  i32x4 r;
  r.x = (a.x & 255) | ((a.y & 255) << 8) | ((a.z & 255) << 16) | (a.w << 24);
  r.y = (b.x & 255) | ((b.y & 255) << 8) | ((b.z & 255) << 16) | (b.w << 24);
  r.z = (c.x & 255) | ((c.y & 255) << 8) | ((c.z & 255) << 16) | (c.w << 24);
  r.w = (d.x & 255) | ((d.y & 255) << 8) | ((d.z & 255) << 16) | (d.w << 24);
  *(i32x4*)(out + i) = r;
}

// ---- lin1: q = requant(gelu(x @ w1^T * a1 + b1)) ----------------------------
__global__ void __launch_bounds__(256)
k_lin1(const int8_t* __restrict__ X, const int8_t* __restrict__ W1,
       const float* __restrict__ B1, const float* __restrict__ pa1,
       const float* __restrict__ psreq, int8_t* __restrict__ Q, int nwg) {
  constexpr int K = D_DIM;
  constexpr int NTN = H_DIM / BN;  // 40
  const int bid = xcd_swizzle(blockIdx.x, nwg);
  const int bn = bid % NTN;
  const int bm = bid / NTN;

  __shared__ __align__(16) int8_t As[BM * BK];
  __shared__ __align__(16) int8_t Bs[BN * BK];

  const int tid = threadIdx.x;
  const int lane = tid & 63;
  const int wid = tid >> 6;
  const int wr = wid >> 1;  // 2x2 waves, each owns 64x64
  const int wc = wid & 1;

  i32x4 acc[4][4] = {};

  const int8_t* Ag = X + (size_t)bm * BM * K;
  const int8_t* Bg = W1 + (size_t)bn * BN * K;

  const int srow = tid >> 2;        // 0..63
  const int scol = (tid & 3) << 4;  // 0,16,32,48

  for (int kt = 0; kt < K; kt += BK) {
    gload_lds16(Ag + (size_t)srow * K + kt + scol, As + tid * 16);
    gload_lds16(Ag + (size_t)(srow + 64) * K + kt + scol, As + 4096 + tid * 16);
    gload_lds16(Bg + (size_t)srow * K + kt + scol, Bs + tid * 16);
    gload_lds16(Bg + (size_t)(srow + 64) * K + kt + scol, Bs + 4096 + tid * 16);
    __syncthreads();

    const int kb = (lane >> 4) << 4;
    const int ar = (wr << 6) + (lane & 15);
    const int br = (wc << 6) + (lane & 15);
    i32x4 af[4], bf[4];
#pragma unroll
    for (int m = 0; m < 4; ++m)
      af[m] = *(const i32x4*)(As + (ar + m * 16) * BK + kb);
#pragma unroll
    for (int n = 0; n < 4; ++n)
      bf[n] = *(const i32x4*)(Bs + (br + n * 16) * BK + kb);
#pragma unroll
    for (int m = 0; m < 4; ++m)
#pragma unroll
      for (int n = 0; n < 4; ++n)
        acc[m][n] = __builtin_amdgcn_mfma_i32_16x16x64_i8(af[m], bf[n], acc[m][n], 0, 0, 0);
    __syncthreads();
  }

  const float a1 = *pa1;
  const float rs = 1.0f / (*psreq);   // once per thread; ulp-level diff vs div is harmless
  // C/D layout (16x16): col = lane&15, row = (lane>>4)*4 + reg
  const int rowb = bm * BM + wr * 64 + ((lane >> 4) << 2);
  const int colb = bn * BN + wc * 64 + (lane & 15);
#pragma unroll
  for (int n = 0; n < 4; ++n) {
    const int col = colb + n * 16;
    const float bias = B1[col];
#pragma unroll
    for (int m = 0; m < 4; ++m) {
#pragma unroll
      for (int r = 0; r < 4; ++r) {
        const int row = rowb + m * 16 + r;
        const float h = __builtin_fmaf((float)acc[m][n][r], a1, bias);
        const float g = gelu_fast(h);
        float qf = rintf(g * rs);
        qf = fminf(127.0f, fmaxf(-128.0f, qf));
        Q[(size_t)row * H_DIM + col] = (int8_t)(int)qf;
      }
    }
  }
}

// ---- lin2: out = q @ w2^T * a2 + b2 -----------------------------------------
__global__ void __launch_bounds__(256)
k_lin2(const int8_t* __restrict__ Q, const int8_t* __restrict__ W2,
       const float* __restrict__ B2, const float* __restrict__ pa2,
       float* __restrict__ Out, int nwg) {
  constexpr int K = H_DIM;
  constexpr int NTN = D_DIM / BN;  // 10
  const int bid = xcd_swizzle(blockIdx.x, nwg);
  const int bn = bid % NTN;
  const int bm = bid / NTN;

  __shared__ __align__(16) int8_t As[BM * BK];
  __shared__ __align__(16) int8_t Bs[BN * BK];

  const int tid = threadIdx.x;
  const int lane = tid & 63;
  const int wid = tid >> 6;
  const int wr = wid >> 1;
  const int wc = wid & 1;

  i32x4 acc[4][4] = {};

  const int8_t* Ag = Q + (size_t)bm * BM * K;
  const int8_t* Bg = W2 + (size_t)bn * BN * K;

  const int srow = tid >> 2;
  const int scol = (tid & 3) << 4;

  for (int kt = 0; kt < K; kt += BK) {
    gload_lds16(Ag + (size_t)srow * K + kt + scol, As + tid * 16);
    gload_lds16(Ag + (size_t)(srow + 64) * K + kt + scol, As + 4096 + tid * 16);
    gload_lds16(Bg + (size_t)srow * K + kt + scol, Bs + tid * 16);
    gload_lds16(Bg + (size_t)(srow + 64) * K + kt + scol, Bs + 4096 + tid * 16);
    __syncthreads();

    const int kb = (lane >> 4) << 4;
    const int ar = (wr << 6) + (lane & 15);
    const int br = (wc << 6) + (lane & 15);
    i32x4 af[4], bf[4];
#pragma unroll
    for (int m = 0; m < 4; ++m)
      af[m] = *(const i32x4*)(As + (ar + m * 16) * BK + kb);
#pragma unroll
    for (int n = 0; n < 4; ++n)
      bf[n] = *(const i32x4*)(Bs + (br + n * 16) * BK + kb);
#pragma unroll
    for (int m = 0; m < 4; ++m)
#pragma unroll
      for (int n = 0; n < 4; ++n)
        acc[m][n] = __builtin_amdgcn_mfma_i32_16x16x64_i8(af[m], bf[n], acc[m][n], 0, 0, 0);
    __syncthreads();
  }

  const float a2 = *pa2;
  const int rowb = bm * BM + wr * 64 + ((lane >> 4) << 2);
  const int colb = bn * BN + wc * 64 + (lane & 15);
#pragma unroll
  for (int n = 0; n < 4; ++n) {
    const int col = colb + n * 16;
    const float bias = B2[col];
#pragma unroll
    for (int m = 0; m < 4; ++m) {
#pragma unroll
      for (int r = 0; r < 4; ++r) {
        const int row = rowb + m * 16 + r;
        Out[(size_t)row * D_DIM + col] = __builtin_fmaf((float)acc[m][n][r], a2, bias);
      }
    }
  }
}

extern "C" void kernel_launch(void* const* d_in, const int* in_sizes, int n_in,
                              void* d_out, int out_size, void* d_ws, size_t ws_size,
                              hipStream_t stream) {
  (void)in_sizes; (void)n_in; (void)out_size;
  const int*   x32  = (const int*)d_in[0];
  const int*   w132 = (const int*)d_in[1];
  const float* b1   = (const float*)d_in[2];
  const int*   w232 = (const int*)d_in[3];
  const float* b2   = (const float*)d_in[4];
  const float* a1   = (const float*)d_in[5];
  const float* sreq = (const float*)d_in[6];
  const float* a2   = (const float*)d_in[7];
  float* out = (float*)d_out;

  const int M = 4 * 4096;                       // 16384 tokens
  const size_t WN = (size_t)H_DIM * D_DIM;      // 6,553,600 weights each

  int8_t* w1p  = (int8_t*)d_ws;
  int8_t* w2p  = w1p + WN;
  int8_t* base = w2p + WN;

  size_t avail = ws_size > 2 * WN ? ws_size - 2 * WN : 0;
  size_t rows = avail / (size_t)(D_DIM + H_DIM);
  int Mc = (int)((rows / BM) * BM);
  if (Mc > M) Mc = M;
  if (Mc < BM) Mc = BM;

  k_pack<<<(int)(WN / 4096), 256, 0, stream>>>(w132, w1p, (long)WN);
  k_pack<<<(int)(WN / 4096), 256, 0, stream>>>(w232, w2p, (long)WN);

  for (int m0 = 0; m0 < M; m0 += Mc) {
    const int mc = (M - m0 < Mc) ? (M - m0) : Mc;
    int8_t* xp = base;
    int8_t* q  = base + (size_t)Mc * D_DIM;
    const size_t nx = (size_t)mc * D_DIM;
    const int nwg1 = (mc / BM) * (H_DIM / BN);
    const int nwg2 = (mc / BM) * (D_DIM / BN);
    k_pack<<<(int)(nx / 4096), 256, 0, stream>>>(x32 + (size_t)m0 * D_DIM, xp, (long)nx);
    k_lin1<<<nwg1, 256, 0, stream>>>(xp, w1p, b1, a1, sreq, q, nwg1);
    k_lin2<<<nwg2, 256, 0, stream>>>(q, w2p, b2, a2, out + (size_t)m0 * D_DIM, nwg2);
  }
}